// Round 1
// baseline (382.094 us; speedup 1.0000x reference)
//
#include <hip/hip_runtime.h>

// Cosine-sim attention, B=4 H=8 d=128 T=2048, alpha=5.
// Strategy: fp32 normalize prepass -> bf16 ws tensors; flash-attention with
// 16x16x32 bf16 MFMA computing S^T (keys=M, queries=N) so softmax is per-lane
// + 2 shuffles, and O^T C-layout stores coalesced along T.

#define T_SEQ 2048
#define DH 128
#define BH 32   // B*H

typedef float f32x4 __attribute__((ext_vector_type(4)));
typedef __bf16 bf16x8 __attribute__((ext_vector_type(8)));

// ---------- prepass: per-(bh,t) L2 norm over 128 channels, scale, transpose ----------
// src: [bh][128][T] fp32 ; dst: [bh][T][128] bf16 (value * scale / max(norm,eps))
__global__ __launch_bounds__(256) void norm_transpose_kernel(
    const float* __restrict__ src, __bf16* __restrict__ dst, float scale) {
  __shared__ float tile[DH * 68];   // [ch][t] pad 68 -> 2-way-free banks
  __shared__ float part[4][64];
  __shared__ float inv_t[64];
  const int bh = blockIdx.x >> 5;
  const int t0 = (blockIdx.x & 31) * 64;
  const int tid = threadIdx.x;

#pragma unroll
  for (int it = 0; it < 8; ++it) {
    int c = tid + it * 256;
    int ch = c >> 4;
    int t4 = (c & 15) * 4;
    f32x4 v = *(const f32x4*)(src + (size_t)(bh * DH + ch) * T_SEQ + t0 + t4);
    *(f32x4*)(tile + ch * 68 + t4) = v;
  }
  __syncthreads();
  const int tt = tid & 63;
  const int seg = tid >> 6;
  float ss = 0.f;
#pragma unroll
  for (int i = 0; i < 32; ++i) {
    float x = tile[(seg * 32 + i) * 68 + tt];
    ss += x * x;
  }
  part[seg][tt] = ss;
  __syncthreads();
  if (tid < 64) {
    float n = sqrtf(part[0][tid] + part[1][tid] + part[2][tid] + part[3][tid]);
    inv_t[tid] = scale / fmaxf(n, 1e-12f);  // matches F.normalize semantics
  }
  __syncthreads();
  const float inv = inv_t[tt];
  __bf16* drow = dst + (size_t)(bh * T_SEQ + t0 + tt) * DH + seg * 32;
#pragma unroll
  for (int cc = 0; cc < 4; ++cc) {
    bf16x8 ob;
#pragma unroll
    for (int j = 0; j < 8; ++j)
      ob[j] = (__bf16)(tile[(seg * 32 + cc * 8 + j) * 68 + tt] * inv);
    *(bf16x8*)(drow + cc * 8) = ob;
  }
}

// ---------- prepass: cast v fp32 -> bf16, layout preserved ----------
__global__ __launch_bounds__(256) void cast_bf16_kernel(
    const float* __restrict__ src, __bf16* __restrict__ dst, int n8) {
  int i = blockIdx.x * 256 + threadIdx.x;
  if (i >= n8) return;
  f32x4 a = *(const f32x4*)(src + (size_t)i * 8);
  f32x4 b = *(const f32x4*)(src + (size_t)i * 8 + 4);
  bf16x8 ob;
  ob[0] = (__bf16)a[0]; ob[1] = (__bf16)a[1]; ob[2] = (__bf16)a[2]; ob[3] = (__bf16)a[3];
  ob[4] = (__bf16)b[0]; ob[5] = (__bf16)b[1]; ob[6] = (__bf16)b[2]; ob[7] = (__bf16)b[3];
  *(bf16x8*)(dst + (size_t)i * 8) = ob;
}

// ---------- flash attention ----------
// qn: [bh][T][128] bf16 (alpha folded) ; kn: [bh][T][128] bf16 ; vb: [bh][128][T] bf16
// out: [bh][128][T] fp32
// Block: 256 thr = 4 waves; 64 queries/block (16/wave); K-loop step 64 keys.
__global__ __launch_bounds__(256, 2) void attn_kernel(
    const __bf16* __restrict__ qn, const __bf16* __restrict__ kn,
    const __bf16* __restrict__ vb, float* __restrict__ out) {
  __shared__ __bf16 lds_k[64 * 136];     // [key][ch]  pad 8 bf16
  __shared__ __bf16 lds_v[DH * 72];      // [ch][key]  pad 8 bf16
  __shared__ float p_buf[4 * 16 * 68];   // per-wave [q][key] pad 4 fp32

  const int bh = blockIdx.x >> 5;
  const int q0 = (blockIdx.x & 31) * 64;
  const int tid = threadIdx.x;
  const int w = tid >> 6;
  const int lane = tid & 63;
  const int qi = lane & 15;   // N-index (query) for B-frags / C cols
  const int g = lane >> 4;    // quad

  // Persistent Q B-fragments: B[n=q=lane&15][k=ch=s*32+g*8+j]
  bf16x8 qf[4];
  {
    const __bf16* qrow = qn + (size_t)(bh * T_SEQ + q0 + w * 16 + qi) * DH + g * 8;
#pragma unroll
    for (int s = 0; s < 4; ++s) qf[s] = *(const bf16x8*)(qrow + s * 32);
  }

  f32x4 o_acc[8];   // O^T tile: M=128 ch (8 mtiles), N=16 q
#pragma unroll
  for (int i = 0; i < 8; ++i) o_acc[i] = (f32x4)(0.f);
  float m_run = -__builtin_inff();
  float l_run = 0.f;

  float* pw = p_buf + w * (16 * 68) + qi * 68;  // this lane's query row base... (per-wave region)
  const __bf16* kbase = kn + (size_t)bh * T_SEQ * DH;
  const __bf16* vbase = vb + (size_t)bh * DH * T_SEQ;

  for (int k0 = 0; k0 < T_SEQ; k0 += 64) {
    // stage K tile [64 key][128 ch] and V tile [128 ch][64 key], 16B/thread/iter
#pragma unroll
    for (int it = 0; it < 4; ++it) {
      int c = tid + it * 256;
      int key = c >> 4;
      int cs = (c & 15) * 8;
      *(bf16x8*)(lds_k + key * 136 + cs) =
          *(const bf16x8*)(kbase + (size_t)(k0 + key) * DH + cs);
    }
#pragma unroll
    for (int it = 0; it < 4; ++it) {
      int c = tid + it * 256;
      int ch = c >> 3;
      int ks = (c & 7) * 8;
      *(bf16x8*)(lds_v + ch * 72 + ks) =
          *(const bf16x8*)(vbase + (size_t)ch * T_SEQ + k0 + ks);
    }
    __syncthreads();

    // S^T[key, q] = sum_ch kn_t[key][ch] * qn_t[q][ch]  (A = K rows, B = Q)
    f32x4 sacc[4];
#pragma unroll
    for (int mt = 0; mt < 4; ++mt) {
      f32x4 acc = (f32x4)(0.f);
#pragma unroll
      for (int s = 0; s < 4; ++s) {
        bf16x8 a = *(const bf16x8*)(lds_k + (mt * 16 + qi) * 136 + s * 32 + g * 8);
        acc = __builtin_amdgcn_mfma_f32_16x16x32_bf16(a, qf[s], acc, 0, 0, 0);
      }
      sacc[mt] = acc;
    }

    // online softmax for query qi: lane holds keys {mt*16 + g*4 + r}
    float tmax = -__builtin_inff();
#pragma unroll
    for (int mt = 0; mt < 4; ++mt)
#pragma unroll
      for (int r = 0; r < 4; ++r) tmax = fmaxf(tmax, sacc[mt][r]);
    tmax = fmaxf(tmax, __shfl_xor(tmax, 16, 64));
    tmax = fmaxf(tmax, __shfl_xor(tmax, 32, 64));
    const float m_new = fmaxf(m_run, tmax);
    const float corr = __expf(m_run - m_new);  // first iter: exp(-inf)=0

    float rsum = 0.f;
#pragma unroll
    for (int mt = 0; mt < 4; ++mt) {
      f32x4 p;
#pragma unroll
      for (int r = 0; r < 4; ++r) {
        float e = __expf(sacc[mt][r] - m_new);
        p[r] = e;
        rsum += e;
      }
      // contiguous 4 keys per lane -> b128 write into per-wave P^T buffer [q][key]
      *(f32x4*)(pw + mt * 16 + g * 4) = p;
    }
    rsum += __shfl_xor(rsum, 16, 64);
    rsum += __shfl_xor(rsum, 32, 64);
    l_run = l_run * corr + rsum;
    m_run = m_new;
#pragma unroll
    for (int i = 0; i < 8; ++i) {
      o_acc[i][0] *= corr; o_acc[i][1] *= corr;
      o_acc[i][2] *= corr; o_acc[i][3] *= corr;
    }

    // O^T += V * P^T : A[m=ch][k=key] from lds_v, B[n=q][k=key] from p_buf
    // (same-wave LDS write->read: overlapping ranges force compiler lgkmcnt order)
#pragma unroll
    for (int st = 0; st < 2; ++st) {
      f32x4 pa = *(const f32x4*)(pw + st * 32 + g * 8);
      f32x4 pb4 = *(const f32x4*)(pw + st * 32 + g * 8 + 4);
      bf16x8 pf;
      pf[0] = (__bf16)pa[0];  pf[1] = (__bf16)pa[1];
      pf[2] = (__bf16)pa[2];  pf[3] = (__bf16)pa[3];
      pf[4] = (__bf16)pb4[0]; pf[5] = (__bf16)pb4[1];
      pf[6] = (__bf16)pb4[2]; pf[7] = (__bf16)pb4[3];
#pragma unroll
      for (int mt = 0; mt < 8; ++mt) {
        bf16x8 a = *(const bf16x8*)(lds_v + (mt * 16 + qi) * 72 + st * 32 + g * 8);
        o_acc[mt] = __builtin_amdgcn_mfma_f32_16x16x32_bf16(a, pf, o_acc[mt], 0, 0, 0);
      }
    }
    __syncthreads();
  }

  // epilogue: O^T C-layout row = ch = mt*16 + g*4 + r, col = q = qi; divide by l
  const float rinv = 1.f / l_run;
  const int tq = q0 + w * 16 + qi;
#pragma unroll
  for (int mt = 0; mt < 8; ++mt) {
#pragma unroll
    for (int r = 0; r < 4; ++r) {
      int ch = mt * 16 + g * 4 + r;
      out[(size_t)(bh * DH + ch) * T_SEQ + tq] = o_acc[mt][r] * rinv;
    }
  }
}

extern "C" void kernel_launch(void* const* d_in, const int* in_sizes, int n_in,
                              void* d_out, int out_size, void* d_ws, size_t ws_size,
                              hipStream_t stream) {
  const float* q = (const float*)d_in[0];
  const float* k = (const float*)d_in[1];
  const float* v = (const float*)d_in[2];
  float* out = (float*)d_out;
  const size_t n = (size_t)BH * T_SEQ * DH;  // 8,388,608 elems per tensor
  if (ws_size < 3 * n * sizeof(__bf16)) return;  // need ~50.3 MB scratch
  __bf16* qn = (__bf16*)d_ws;
  __bf16* kn = qn + n;
  __bf16* vbf = kn + n;

  norm_transpose_kernel<<<dim3(BH * 32), dim3(256), 0, stream>>>(q, qn, 5.0f);
  norm_transpose_kernel<<<dim3(BH * 32), dim3(256), 0, stream>>>(k, kn, 1.0f);
  cast_bf16_kernel<<<dim3((int)(n / 8 / 256)), dim3(256), 0, stream>>>(v, vbf, (int)(n / 8));
  attn_kernel<<<dim3(1024), dim3(256), 0, stream>>>(qn, kn, vbf, out);
}

// Round 2
// 241.453 us; speedup vs baseline: 1.5825x; 1.5825x over previous
//
#include <hip/hip_runtime.h>

// Cosine-sim attention, B=4 H=8 d=128 T=2048, alpha=5.
// R2: frag-ordered K/V LDS staging via global_load_lds gather (no bank
// conflicts, no VGPR staging), 32 q/wave (A-frag reuse across 2 n-tiles),
// bf16 P round-trip, coalesced prepass.

#define T_SEQ 2048
#define DH 128
#define BH 32   // B*H

typedef float f32x4 __attribute__((ext_vector_type(4)));
typedef __bf16 bf16x8 __attribute__((ext_vector_type(8)));
typedef __bf16 bf16x4 __attribute__((ext_vector_type(4)));

__device__ __forceinline__ void async_copy16(const void* g, void* l) {
  __builtin_amdgcn_global_load_lds(
      (const __attribute__((address_space(1))) void*)g,
      (__attribute__((address_space(3))) void*)l, 16, 0, 0);
}

// ---------- prepass: per-(bh,t) L2 norm over 128 ch, scale, transpose ----------
// src: [bh][128][T] fp32 ; dst: [bh][T][128] bf16 (value * scale / max(norm,eps))
// Block: 64 t x 128 ch. Loads coalesced along T; stores coalesced along ch.
__global__ __launch_bounds__(256) void norm_transpose_kernel(
    const float* __restrict__ src, __bf16* __restrict__ dst, float scale) {
  __shared__ float tile[64 * 133];   // [t][ch] stride 133
  __shared__ float part[4][64];
  __shared__ float inv_t[64];
  const int bh = blockIdx.x >> 5;
  const int t0 = (blockIdx.x & 31) * 64;
  const int tid = threadIdx.x;

  // load + LDS transpose (scalar write side, ~2-way banks at stride 133)
#pragma unroll
  for (int it = 0; it < 8; ++it) {
    int c = it * 256 + tid;          // 0..2047
    int ch = c >> 4;
    int t4 = (c & 15) * 4;
    f32x4 v = *(const f32x4*)(src + (size_t)(bh * DH + ch) * T_SEQ + t0 + t4);
#pragma unroll
    for (int i = 0; i < 4; ++i) tile[(t4 + i) * 133 + ch] = v[i];
  }
  __syncthreads();
  // norms: 4 threads per t, each sums 32 ch
  const int t = tid & 63;
  const int seg = tid >> 6;
  float ss = 0.f;
#pragma unroll
  for (int i = 0; i < 8; ++i) {
    f32x4 x = *(const f32x4*)(tile + t * 133 + seg * 32 + i * 4);
    ss += x[0]*x[0] + x[1]*x[1] + x[2]*x[2] + x[3]*x[3];
  }
  part[seg][t] = ss;
  __syncthreads();
  if (tid < 64) {
    float n = sqrtf(part[0][tid] + part[1][tid] + part[2][tid] + part[3][tid]);
    inv_t[tid] = scale / fmaxf(n, 1e-12f);
  }
  __syncthreads();
  // store: thread -> (t_o = tid>>2, 32 ch chunk); lanes cover ch then t: coalesced
  const int t_o = tid >> 2;
  const int c0 = (tid & 3) * 32;
  const float inv = inv_t[t_o];
  __bf16* drow = dst + (size_t)(bh * T_SEQ + t0 + t_o) * DH + c0;
#pragma unroll
  for (int cc = 0; cc < 4; ++cc) {
    f32x4 a = *(const f32x4*)(tile + t_o * 133 + c0 + cc * 8);
    f32x4 b = *(const f32x4*)(tile + t_o * 133 + c0 + cc * 8 + 4);
    bf16x8 ob;
    ob[0] = (__bf16)(a[0]*inv); ob[1] = (__bf16)(a[1]*inv);
    ob[2] = (__bf16)(a[2]*inv); ob[3] = (__bf16)(a[3]*inv);
    ob[4] = (__bf16)(b[0]*inv); ob[5] = (__bf16)(b[1]*inv);
    ob[6] = (__bf16)(b[2]*inv); ob[7] = (__bf16)(b[3]*inv);
    *(bf16x8*)(drow + cc * 8) = ob;
  }
}

// ---------- prepass: cast v fp32 -> bf16, layout preserved ----------
__global__ __launch_bounds__(256) void cast_bf16_kernel(
    const float* __restrict__ src, __bf16* __restrict__ dst, int n8) {
  int i = blockIdx.x * 256 + threadIdx.x;
  if (i >= n8) return;
  f32x4 a = *(const f32x4*)(src + (size_t)i * 8);
  f32x4 b = *(const f32x4*)(src + (size_t)i * 8 + 4);
  bf16x8 ob;
  ob[0] = (__bf16)a[0]; ob[1] = (__bf16)a[1]; ob[2] = (__bf16)a[2]; ob[3] = (__bf16)a[3];
  ob[4] = (__bf16)b[0]; ob[5] = (__bf16)b[1]; ob[6] = (__bf16)b[2]; ob[7] = (__bf16)b[3];
  *(bf16x8*)(dst + (size_t)i * 8) = ob;
}

// ---------- flash attention ----------
// qn/kn: [bh][T][128] bf16 (alpha folded into qn) ; vb: [bh][128][T] bf16
// out: [bh][128][T] fp32
// Block: 256 thr = 4 waves; 128 queries/block (32/wave, 2 n-tiles); 64 keys/iter.
// K/V staged frag-ordered: frag f occupies lds[f*512 .. f*512+511] bf16,
// lane-linear (lane*8 elems) -> conflict-free b128 reads.
__global__ __launch_bounds__(256, 2) void attn_kernel(
    const __bf16* __restrict__ qn, const __bf16* __restrict__ kn,
    const __bf16* __restrict__ vb, float* __restrict__ out) {
  __shared__ __bf16 lds_k[16 * 512];    // 16 frags (mt0..3 x s0..3)   16 KB
  __shared__ __bf16 lds_v[16 * 512];    // 16 frags (mt0..7 x st0..1)  16 KB
  __shared__ __bf16 p_buf[8 * 16 * 68]; // per (wave,nt): [16 q][68]   17 KB

  const int bh = blockIdx.x >> 4;
  const int q0 = (blockIdx.x & 15) * 128;
  const int tid = threadIdx.x;
  const int w = tid >> 6;
  const int lane = tid & 63;
  const int qi = lane & 15;
  const int g = lane >> 4;

  const __bf16* kbase = kn + (size_t)bh * (T_SEQ * DH);
  const __bf16* vbase = vb + (size_t)bh * (DH * T_SEQ);

  // persistent Q B-frags: B[n=q][k=ch], n=lane&15, k=s*32+g*8+j  (R1-verified)
  bf16x8 qf[2][4];
#pragma unroll
  for (int nt = 0; nt < 2; ++nt) {
    const __bf16* qrow =
        qn + (size_t)(bh * T_SEQ + q0 + w * 32 + nt * 16 + qi) * DH + g * 8;
#pragma unroll
    for (int s = 0; s < 4; ++s) qf[nt][s] = *(const bf16x8*)(qrow + s * 32);
  }

  f32x4 o_acc[2][8];
#pragma unroll
  for (int nt = 0; nt < 2; ++nt)
#pragma unroll
    for (int i = 0; i < 8; ++i) o_acc[nt][i] = (f32x4)(0.f);
  float m_run[2] = {-__builtin_inff(), -__builtin_inff()};
  float l_run[2] = {0.f, 0.f};

  for (int k0 = 0; k0 < T_SEQ; k0 += 64) {
    // ---- async staging: each wave issues 8 of the 32 fragment-gathers ----
#pragma unroll
    for (int i = 0; i < 8; ++i) {
      const int I = w * 8 + i;   // wave-uniform
      if (I < 16) {
        const int mt = I >> 2, s = I & 3;
        const __bf16* ga =
            kbase + (size_t)(k0 + mt * 16 + qi) * DH + s * 32 + g * 8;
        async_copy16(ga, lds_k + I * 512);
      } else {
        const int f = I - 16;
        const int mt = f >> 1, st = f & 1;
        const __bf16* ga =
            vbase + (size_t)(mt * 16 + qi) * T_SEQ + k0 + st * 32 + g * 8;
        async_copy16(ga, lds_v + f * 512);
      }
    }
    __syncthreads();   // compiler emits vmcnt(0) drain before barrier

    // ---- S^T = K . Q : A-frag read once, used by both n-tiles ----
    f32x4 sacc[2][4];
#pragma unroll
    for (int nt = 0; nt < 2; ++nt)
#pragma unroll
      for (int mt = 0; mt < 4; ++mt) sacc[nt][mt] = (f32x4)(0.f);
#pragma unroll
    for (int s = 0; s < 4; ++s) {
#pragma unroll
      for (int mt = 0; mt < 4; ++mt) {
        bf16x8 a = *(const bf16x8*)(lds_k + ((mt * 4 + s) * 64 + lane) * 8);
        sacc[0][mt] = __builtin_amdgcn_mfma_f32_16x16x32_bf16(a, qf[0][s], sacc[0][mt], 0, 0, 0);
        sacc[1][mt] = __builtin_amdgcn_mfma_f32_16x16x32_bf16(a, qf[1][s], sacc[1][mt], 0, 0, 0);
      }
    }

    // ---- online softmax per n-tile; P -> per-wave bf16 LDS ----
#pragma unroll
    for (int nt = 0; nt < 2; ++nt) {
      float tmax = -__builtin_inff();
#pragma unroll
      for (int mt = 0; mt < 4; ++mt)
#pragma unroll
        for (int r = 0; r < 4; ++r) tmax = fmaxf(tmax, sacc[nt][mt][r]);
      tmax = fmaxf(tmax, __shfl_xor(tmax, 16, 64));
      tmax = fmaxf(tmax, __shfl_xor(tmax, 32, 64));
      const float m_new = fmaxf(m_run[nt], tmax);
      const float corr = __expf(m_run[nt] - m_new);

      __bf16* pw = p_buf + (size_t)((w * 2 + nt) * 16 + qi) * 68;
      float rsum = 0.f;
#pragma unroll
      for (int mt = 0; mt < 4; ++mt) {
        bf16x4 pb;
#pragma unroll
        for (int r = 0; r < 4; ++r) {
          float e = __expf(sacc[nt][mt][r] - m_new);
          rsum += e;
          pb[r] = (__bf16)e;
        }
        *(bf16x4*)(pw + mt * 16 + g * 4) = pb;
      }
      rsum += __shfl_xor(rsum, 16, 64);
      rsum += __shfl_xor(rsum, 32, 64);
      l_run[nt] = l_run[nt] * corr + rsum;
      m_run[nt] = m_new;
#pragma unroll
      for (int i = 0; i < 8; ++i) {
        o_acc[nt][i][0] *= corr; o_acc[nt][i][1] *= corr;
        o_acc[nt][i][2] *= corr; o_acc[nt][i][3] *= corr;
      }
    }

    // ---- O^T += V . P^T : V A-frag read once, used by both n-tiles ----
#pragma unroll
    for (int st = 0; st < 2; ++st) {
      bf16x8 pf0 = *(const bf16x8*)(p_buf + (size_t)((w * 2 + 0) * 16 + qi) * 68 + st * 32 + g * 8);
      bf16x8 pf1 = *(const bf16x8*)(p_buf + (size_t)((w * 2 + 1) * 16 + qi) * 68 + st * 32 + g * 8);
#pragma unroll
      for (int mt = 0; mt < 8; ++mt) {
        bf16x8 a = *(const bf16x8*)(lds_v + ((mt * 2 + st) * 64 + lane) * 8);
        o_acc[0][mt] = __builtin_amdgcn_mfma_f32_16x16x32_bf16(a, pf0, o_acc[0][mt], 0, 0, 0);
        o_acc[1][mt] = __builtin_amdgcn_mfma_f32_16x16x32_bf16(a, pf1, o_acc[1][mt], 0, 0, 0);
      }
    }
    __syncthreads();   // protect lds_k/lds_v before next iter's DMA
  }

  // ---- epilogue: C row = ch = mt*16 + g*4 + r, col = q (R1-verified) ----
#pragma unroll
  for (int nt = 0; nt < 2; ++nt) {
    const float rinv = 1.f / l_run[nt];
    const int tq = q0 + w * 32 + nt * 16 + qi;
#pragma unroll
    for (int mt = 0; mt < 8; ++mt) {
#pragma unroll
      for (int r = 0; r < 4; ++r) {
        int ch = mt * 16 + g * 4 + r;
        out[(size_t)(bh * DH + ch) * T_SEQ + tq] = o_acc[nt][mt][r] * rinv;
      }
    }
  }
}

extern "C" void kernel_launch(void* const* d_in, const int* in_sizes, int n_in,
                              void* d_out, int out_size, void* d_ws, size_t ws_size,
                              hipStream_t stream) {
  const float* q = (const float*)d_in[0];
  const float* k = (const float*)d_in[1];
  const float* v = (const float*)d_in[2];
  float* out = (float*)d_out;
  const size_t n = (size_t)BH * T_SEQ * DH;
  if (ws_size < 3 * n * sizeof(__bf16)) return;
  __bf16* qn = (__bf16*)d_ws;
  __bf16* kn = qn + n;
  __bf16* vbf = kn + n;

  norm_transpose_kernel<<<dim3(BH * 32), dim3(256), 0, stream>>>(q, qn, 5.0f);
  norm_transpose_kernel<<<dim3(BH * 32), dim3(256), 0, stream>>>(k, kn, 1.0f);
  cast_bf16_kernel<<<dim3((int)(n / 8 / 256)), dim3(256), 0, stream>>>(v, vbf, (int)(n / 8));
  attn_kernel<<<dim3(512), dim3(256), 0, stream>>>(qn, kn, vbf, out);
}

// Round 3
// 214.722 us; speedup vs baseline: 1.7795x; 1.1245x over previous
//
#include <hip/hip_runtime.h>

// Cosine-sim attention, B=4 H=8 d=128 T=2048, alpha=5.
// R3: bounded-logit softmax (no max-tracking: alpha*cos <= 5), K+V LDS
// double-buffer with ONE barrier/iter (DMA in flight a full iteration),
// Q-norm fused into attn, K-norm + V-cast fused into one prepass kernel.

#define T_SEQ 2048
#define DH 128
#define BH 32   // B*H

typedef float f32x4 __attribute__((ext_vector_type(4)));
typedef __bf16 bf16x8 __attribute__((ext_vector_type(8)));
typedef __bf16 bf16x4 __attribute__((ext_vector_type(4)));

__device__ __forceinline__ void async_copy16(const void* g, void* l) {
  __builtin_amdgcn_global_load_lds(
      (const __attribute__((address_space(1))) void*)g,
      (__attribute__((address_space(3))) void*)l, 16, 0, 0);
}

// ---------- prepass: K norm+transpose (blocks 0..1023) + V cast (1024..5119) ----------
// ksrc: [bh][128][T] fp32 -> kn: [bh][T][128] bf16 (unit-normalized over ch)
// vsrc: fp32 -> vb bf16, layout preserved [bh][128][T]
__global__ __launch_bounds__(256) void prepass_kernel(
    const float* __restrict__ ksrc, const float* __restrict__ vsrc,
    __bf16* __restrict__ kn, __bf16* __restrict__ vb) {
  __shared__ float tile[64 * 133];
  __shared__ float part[4][64];
  __shared__ float inv_t[64];
  const int tid = threadIdx.x;

  if (blockIdx.x >= 1024) {           // ---- V cast: 4096 blocks, 8 elems/thread
    int i = (blockIdx.x - 1024) * 256 + tid;
    f32x4 a = *(const f32x4*)(vsrc + (size_t)i * 8);
    f32x4 b = *(const f32x4*)(vsrc + (size_t)i * 8 + 4);
    bf16x8 ob;
    ob[0] = (__bf16)a[0]; ob[1] = (__bf16)a[1]; ob[2] = (__bf16)a[2]; ob[3] = (__bf16)a[3];
    ob[4] = (__bf16)b[0]; ob[5] = (__bf16)b[1]; ob[6] = (__bf16)b[2]; ob[7] = (__bf16)b[3];
    *(bf16x8*)(vb + (size_t)i * 8) = ob;
    return;
  }

  // ---- K norm + transpose: 64 t x 128 ch per block
  const int bh = blockIdx.x >> 5;
  const int t0 = (blockIdx.x & 31) * 64;
#pragma unroll
  for (int it = 0; it < 8; ++it) {
    int c = it * 256 + tid;
    int ch = c >> 4;
    int t4 = (c & 15) * 4;
    f32x4 v = *(const f32x4*)(ksrc + (size_t)(bh * DH + ch) * T_SEQ + t0 + t4);
#pragma unroll
    for (int i = 0; i < 4; ++i) tile[(t4 + i) * 133 + ch] = v[i];
  }
  __syncthreads();
  const int t = tid & 63;
  const int seg = tid >> 6;
  float ss = 0.f;
#pragma unroll
  for (int i = 0; i < 8; ++i) {
    f32x4 x = *(const f32x4*)(tile + t * 133 + seg * 32 + i * 4);
    ss += x[0]*x[0] + x[1]*x[1] + x[2]*x[2] + x[3]*x[3];
  }
  part[seg][t] = ss;
  __syncthreads();
  if (tid < 64) {
    float n = sqrtf(part[0][tid] + part[1][tid] + part[2][tid] + part[3][tid]);
    inv_t[tid] = 1.f / fmaxf(n, 1e-12f);
  }
  __syncthreads();
  const int t_o = tid >> 2;
  const int c0 = (tid & 3) * 32;
  const float inv = inv_t[t_o];
  __bf16* drow = kn + (size_t)(bh * T_SEQ + t0 + t_o) * DH + c0;
#pragma unroll
  for (int cc = 0; cc < 4; ++cc) {
    f32x4 a = *(const f32x4*)(tile + t_o * 133 + c0 + cc * 8);
    f32x4 b = *(const f32x4*)(tile + t_o * 133 + c0 + cc * 8 + 4);
    bf16x8 ob;
    ob[0] = (__bf16)(a[0]*inv); ob[1] = (__bf16)(a[1]*inv);
    ob[2] = (__bf16)(a[2]*inv); ob[3] = (__bf16)(a[3]*inv);
    ob[4] = (__bf16)(b[0]*inv); ob[5] = (__bf16)(b[1]*inv);
    ob[6] = (__bf16)(b[2]*inv); ob[7] = (__bf16)(b[3]*inv);
    *(bf16x8*)(drow + cc * 8) = ob;
  }
}

// ---------- flash attention ----------
// q: [bh][128][T] fp32 (normalized in-kernel, alpha folded)
// kn: [bh][T][128] bf16 unit-norm ; vb: [bh][128][T] bf16 ; out: [bh][128][T] fp32
// Block: 4 waves, 128 q (32/wave, 2 n-tiles); 64 keys/iter; K/V dbuf, 1 barrier/iter.
__device__ __forceinline__ void stage_tiles(
    const __bf16* kbase, const __bf16* vbase, __bf16* lk, __bf16* lv,
    int koff, int w, int qi, int g) {
#pragma unroll
  for (int i = 0; i < 4; ++i) {
    const int f = w * 4 + i;          // K frag: mt = f>>2, s = f&3
    const int mt = f >> 2, s = f & 3;
    async_copy16(kbase + (size_t)(koff + mt * 16 + qi) * DH + s * 32 + g * 8,
                 lk + f * 512);
  }
#pragma unroll
  for (int i = 0; i < 4; ++i) {
    const int f = w * 4 + i;          // V frag: mt = f>>1, st = f&1
    const int mt = f >> 1, st = f & 1;
    async_copy16(vbase + (size_t)(mt * 16 + qi) * T_SEQ + koff + st * 32 + g * 8,
                 lv + f * 512);
  }
}

__global__ __launch_bounds__(256, 2) void attn_kernel(
    const float* __restrict__ q, const __bf16* __restrict__ kn,
    const __bf16* __restrict__ vb, float* __restrict__ out) {
  __shared__ __align__(16) __bf16 lds_k[2][16 * 512];   // 32 KB
  __shared__ __align__(16) __bf16 lds_v[2][16 * 512];   // 32 KB
  __shared__ __align__(16) __bf16 p_buf[8 * 1024];      // 16 KB, XOR-swizzled
  // total 81920 B -> exactly 2 blocks/CU

  const int bh = blockIdx.x >> 4;
  const int q0 = (blockIdx.x & 15) * 128;
  const int tid = threadIdx.x;
  const int w = tid >> 6, lane = tid & 63;
  const int qi = lane & 15, g = lane >> 4;

  const __bf16* kbase = kn + (size_t)bh * (T_SEQ * DH);
  const __bf16* vbase = vb + (size_t)bh * (DH * T_SEQ);
  const float* qsrc = q + (size_t)bh * (DH * T_SEQ);

  // kick iter-0 staging first; Q-norm below overlaps the DMA latency
  stage_tiles(kbase, vbase, lds_k[0], lds_v[0], 0, w, qi, g);

  // fused Q normalize (alpha folded): qf = B[n=q][k=ch] frags
  bf16x8 qf[2][4];
#pragma unroll
  for (int nt = 0; nt < 2; ++nt) {
    const int t = q0 + w * 32 + nt * 16 + qi;
    float xv[32];
    float ss = 0.f;
#pragma unroll
    for (int s = 0; s < 4; ++s)
#pragma unroll
      for (int j = 0; j < 8; ++j) {
        float x = qsrc[(size_t)(s * 32 + g * 8 + j) * T_SEQ + t];
        xv[s * 8 + j] = x;
        ss += x * x;
      }
    ss += __shfl_xor(ss, 16, 64);   // sum across the 4 g-quads (same qi)
    ss += __shfl_xor(ss, 32, 64);
    const float inv = 5.0f / fmaxf(sqrtf(ss), 1e-12f);
#pragma unroll
    for (int s = 0; s < 4; ++s) {
      bf16x8 f;
#pragma unroll
      for (int j = 0; j < 8; ++j) f[j] = (__bf16)(xv[s * 8 + j] * inv);
      qf[nt][s] = f;
    }
  }

  f32x4 o_acc[2][8];
#pragma unroll
  for (int nt = 0; nt < 2; ++nt)
#pragma unroll
    for (int i = 0; i < 8; ++i) o_acc[nt][i] = (f32x4)(0.f);
  float lsum[2] = {0.f, 0.f};

  const int swz = (qi & 7) << 3;
  __bf16* pw0 = p_buf + (w * 2 + 0) * 1024 + qi * 64;
  __bf16* pw1 = p_buf + (w * 2 + 1) * 1024 + qi * 64;

  for (int it = 0; it < 32; ++it) {
    __syncthreads();   // drains own DMA (issued a full iter ago); fences buffers
    const int cur = it & 1;
    if (it + 1 < 32)   // prefetch next tiles into the other buffer
      stage_tiles(kbase, vbase, lds_k[cur ^ 1], lds_v[cur ^ 1],
                  (it + 1) * 64, w, qi, g);

    // ---- S^T = K . Q (A-frag shared across both n-tiles) ----
    const __bf16* lk = lds_k[cur];
    f32x4 sacc[2][4];
#pragma unroll
    for (int nt = 0; nt < 2; ++nt)
#pragma unroll
      for (int mt = 0; mt < 4; ++mt) sacc[nt][mt] = (f32x4)(0.f);
#pragma unroll
    for (int s = 0; s < 4; ++s)
#pragma unroll
      for (int mt = 0; mt < 4; ++mt) {
        bf16x8 a = *(const bf16x8*)(lk + ((mt * 4 + s) * 64 + lane) * 8);
        sacc[0][mt] = __builtin_amdgcn_mfma_f32_16x16x32_bf16(a, qf[0][s], sacc[0][mt], 0, 0, 0);
        sacc[1][mt] = __builtin_amdgcn_mfma_f32_16x16x32_bf16(a, qf[1][s], sacc[1][mt], 0, 0, 0);
      }

    // ---- bounded softmax: p = exp(s), s in [-5,5]; no max tracking ----
#pragma unroll
    for (int nt = 0; nt < 2; ++nt) {
      __bf16* pw = nt ? pw1 : pw0;
      float rs = 0.f;
#pragma unroll
      for (int mt = 0; mt < 4; ++mt) {
        bf16x4 pb;
#pragma unroll
        for (int r = 0; r < 4; ++r) {
          float e = __expf(sacc[nt][mt][r]);
          rs += e;
          pb[r] = (__bf16)e;
        }
        *(bf16x4*)(pw + ((mt * 16 + g * 4) ^ swz)) = pb;
      }
      lsum[nt] += rs;
    }

    // ---- O^T += V . P^T (V A-frag shared across both n-tiles) ----
    const __bf16* lv = lds_v[cur];
#pragma unroll
    for (int st = 0; st < 2; ++st) {
      bf16x8 pf0 = *(const bf16x8*)(pw0 + ((st * 32 + g * 8) ^ swz));
      bf16x8 pf1 = *(const bf16x8*)(pw1 + ((st * 32 + g * 8) ^ swz));
#pragma unroll
      for (int mt = 0; mt < 8; ++mt) {
        bf16x8 a = *(const bf16x8*)(lv + ((mt * 2 + st) * 64 + lane) * 8);
        o_acc[0][mt] = __builtin_amdgcn_mfma_f32_16x16x32_bf16(a, pf0, o_acc[0][mt], 0, 0, 0);
        o_acc[1][mt] = __builtin_amdgcn_mfma_f32_16x16x32_bf16(a, pf1, o_acc[1][mt], 0, 0, 0);
      }
    }
  }

  // ---- epilogue: reduce l across quads; C row=ch=mt*16+g*4+r, col=q ----
#pragma unroll
  for (int nt = 0; nt < 2; ++nt) {
    float l = lsum[nt];
    l += __shfl_xor(l, 16, 64);
    l += __shfl_xor(l, 32, 64);
    const float rinv = 1.f / l;
    const int tq = q0 + w * 32 + nt * 16 + qi;
#pragma unroll
    for (int mt = 0; mt < 8; ++mt)
#pragma unroll
      for (int r = 0; r < 4; ++r)
        out[(size_t)(bh * DH + mt * 16 + g * 4 + r) * T_SEQ + tq] =
            o_acc[nt][mt][r] * rinv;
  }
}

extern "C" void kernel_launch(void* const* d_in, const int* in_sizes, int n_in,
                              void* d_out, int out_size, void* d_ws, size_t ws_size,
                              hipStream_t stream) {
  const float* q = (const float*)d_in[0];
  const float* k = (const float*)d_in[1];
  const float* v = (const float*)d_in[2];
  float* out = (float*)d_out;
  const size_t n = (size_t)BH * T_SEQ * DH;
  if (ws_size < 2 * n * sizeof(__bf16)) return;
  __bf16* kn = (__bf16*)d_ws;
  __bf16* vbf = kn + n;

  prepass_kernel<<<dim3(1024 + 4096), dim3(256), 0, stream>>>(k, v, kn, vbf);
  attn_kernel<<<dim3(512), dim3(256), 0, stream>>>(q, kn, vbf, out);
}